// Round 4
// baseline (330.124 us; speedup 1.0000x reference)
//
#include <hip/hip_runtime.h>

// Problem constants (reference: T=256, L=32, C=8, B=16, D=512)
#define TT 256
#define LL 32
#define CC 8
#define BB 16
#define DD 512
#define D4 (DD / 4)          // 128 float4 per d-row
#define NCHUNK 16            // 16 chunks of 16 frames each
#define CHUNK 16

// Output layout (floats): fc | fm | fb
#define FC_ELEMS ((long)BB * LL * LL * CC * DD)   // 67,108,864 (268.4 MB)
#define FM_ELEMS ((long)BB * LL * LL * DD)        //  8,388,608 (33.6 MB)
#define FM_OFF   FC_ELEMS
#define FB_OFF   (FC_ELEMS + FM_ELEMS)            // 75,497,472

// Workspace layout (floats): csum [B][16][D] | S [B][257][D]
#define CSUM_FLOATS ((long)BB * NCHUNK * DD)      // 131,072
#define S_ROWS      (TT + 1)                      // 257
#define S_OFF_FLOATS CSUM_FLOATS

typedef float v4f __attribute__((ext_vector_type(4)));  // nt-store-compatible

__device__ __forceinline__ float4 f4add(float4 a, float4 b) {
  return make_float4(a.x + b.x, a.y + b.y, a.z + b.z, a.w + b.w);
}
__device__ __forceinline__ float4 f4sub(float4 a, float4 b) {
  return make_float4(a.x - b.x, a.y - b.y, a.z - b.z, a.w - b.w);
}
// Streaming 16B store (nt flag): keep pure-output streams out of L2.
__device__ __forceinline__ void st_nt(float4* p, float4 v) {
  v4f x = {v.x, v.y, v.z, v.w};
  __builtin_nontemporal_store(x, (v4f*)p);
}

// ---------------------------------------------------------------------------
// Kernel A (float4): csum[b][chunk][d4] = sum_{i<16} f[b, 16*chunk+i, d4]
__global__ __launch_bounds__(256) void chunk_sum_kernel(
    const float4* __restrict__ f4, float4* __restrict__ csum4) {
  int tid = blockIdx.x * blockDim.x + threadIdx.x;   // 0 .. 32767
  int d4 = tid & (D4 - 1);
  int chunk = (tid >> 7) & (NCHUNK - 1);
  int b = tid >> 11;
  const float4* fp = f4 + (long)(b * TT + chunk * CHUNK) * D4 + d4;
  float4 s = make_float4(0.f, 0.f, 0.f, 0.f);
#pragma unroll
  for (int i = 0; i < CHUNK; ++i) s = f4add(s, fp[(long)i * D4]);
  csum4[tid] = s;   // cached: re-read next kernel
}

// ---------------------------------------------------------------------------
// Kernel B (float4): exclusive prefix table S[b][p][d] (p in [0,256]) + fb.
// S stores stay cached (consumed by fc_fm); fb stores are nontemporal.
__global__ __launch_bounds__(256) void scan_kernel(
    const float4* __restrict__ f4, const float4* __restrict__ csum4,
    float4* __restrict__ S4, float4* __restrict__ fb4) {
  int tid = blockIdx.x * blockDim.x + threadIdx.x;
  int d4 = tid & (D4 - 1);
  int chunk = (tid >> 7) & (NCHUNK - 1);
  int b = tid >> 11;

  const float4* cp = csum4 + (long)b * NCHUNK * D4 + d4;
  float4 acc = make_float4(0.f, 0.f, 0.f, 0.f);
  for (int i = 0; i < chunk; ++i) acc = f4add(acc, cp[(long)i * D4]);

  const float4* fp = f4 + (long)(b * TT + chunk * CHUNK) * D4 + d4;
  float4* Sp = S4 + ((long)b * S_ROWS + chunk * CHUNK) * D4 + d4;
  if (chunk == 0) Sp[0] = make_float4(0.f, 0.f, 0.f, 0.f);

  float4 vals[CHUNK];
#pragma unroll
  for (int i = 0; i < CHUNK; ++i) {
    vals[i] = fp[(long)i * D4];
    acc = f4add(acc, vals[i]);
    Sp[(long)(i + 1) * D4] = acc;
  }

  // fb[b][d][t]: this thread owns d = 4*d4..4*d4+3, t = chunk*16..+15.
  const float* v = (const float*)vals;  // v[4*i + dd] = f[t=i][d=4*d4+dd]
#pragma unroll
  for (int dd = 0; dd < 4; ++dd) {
    float4* fbp = fb4 + ((long)(b * DD + 4 * d4 + dd) * TT + chunk * CHUNK) / 4;
#pragma unroll
    for (int j = 0; j < 4; ++j) {
      st_nt(&fbp[j],
            make_float4(v[(4 * j + 0) * 4 + dd], v[(4 * j + 1) * 4 + dd],
                        v[(4 * j + 2) * 4 + dd], v[(4 * j + 3) * 4 + dd]));
    }
  }
}

// ---------------------------------------------------------------------------
// Kernel C: fc + fm from prefix differences. All output stores nontemporal
// (310 MB streaming writes must not evict the 8.4 MB S table from L2).
// fc[b,l,m,c,:] = S[8l+(c+1)w] - S[8l+c*w], w = m-l+1; fm = S[8l+8w]-S[8l].
// l > m: write zeros (d_out is poisoned 0xAA before every timed launch).
__global__ __launch_bounds__(128) void fc_fm_kernel(
    const float* __restrict__ S, float* __restrict__ out) {
  int i = blockIdx.x;
  int vblk = ((i & 7) << 11) | (i >> 3);  // XCD-contiguous index (harmless)
  int b = vblk >> 10;
  int l = (vblk >> 5) & (LL - 1);
  int m = vblk & (LL - 1);
  int d4 = threadIdx.x;  // 0..127

  float4* outv = (float4*)out;
  long blm = (long)((b * LL + l) * LL + m);
  long fc_base = blm * CC * D4;               // in float4 units
  long fm_base = FM_OFF / 4 + blm * D4;

  if (l > m) {
    float4 z = make_float4(0.f, 0.f, 0.f, 0.f);
#pragma unroll
    for (int c = 0; c < CC; ++c) st_nt(&outv[fc_base + (long)c * D4 + d4], z);
    st_nt(&outv[fm_base + d4], z);
    return;
  }

  int w = m - l + 1;
  const float4* S4 = (const float4*)S;
  long srow = (long)b * S_ROWS;

  float4 s[9];
#pragma unroll
  for (int c = 0; c <= 8; ++c) {
    int p = 8 * l + c * w;
    s[c] = S4[(srow + p) * D4 + d4];
  }

#pragma unroll
  for (int c = 0; c < CC; ++c)
    st_nt(&outv[fc_base + (long)c * D4 + d4], f4sub(s[c + 1], s[c]));
  st_nt(&outv[fm_base + d4], f4sub(s[8], s[0]));
}

// ---------------------------------------------------------------------------
extern "C" void kernel_launch(void* const* d_in, const int* in_sizes, int n_in,
                              void* d_out, int out_size, void* d_ws, size_t ws_size,
                              hipStream_t stream) {
  const float4* f4 = (const float4*)d_in[0];
  // d_in[1] is Wc — fully encoded in the closed-form index ranges.
  float* out = (float*)d_out;

  float4* csum4 = (float4*)d_ws;                              // 512 KB
  float4* S4 = (float4*)((float*)d_ws + S_OFF_FLOATS);        // 8.4 MB
  float4* fb4 = (float4*)(out + FB_OFF);

  {
    int total4 = BB * NCHUNK * D4;  // 32768 threads
    chunk_sum_kernel<<<total4 / 256, 256, 0, stream>>>(f4, csum4);
    scan_kernel<<<total4 / 256, 256, 0, stream>>>(f4, csum4, S4, fb4);
  }
  {
    fc_fm_kernel<<<BB * LL * LL, 128, 0, stream>>>((const float*)S4, out);
  }
}